// Round 4
// baseline (63.953 us; speedup 1.0000x reference)
//
#include <hip/hip_runtime.h>

namespace {
constexpr int kV    = 21;
constexpr int kNCh  = 1344;         // V*C_OUT
constexpr int kInner = kNCh * 256;  // 344064 elements per n

typedef float f32x4 __attribute__((ext_vector_type(4)));

// workspace layout (floats)
constexpr int X4_OFF = 0;                          // [64][3][4][21] = 16128
constexpr int U_OFF  = 16384;                      // [64][256][21][3] = 1032192
constexpr int ST_OFF = U_OFF + 64 * 256 * 21 * 3;  // [1344][2]
}

// ---------------------------------------------------------------------------
// k1: X4[n][ci][q][v] = sum_{t=q*64..q*64+63} x[n][ci][t][v]
// one block per (n,q): coalesced f32x4 loads -> LDS -> 2-stage reduce
// ---------------------------------------------------------------------------
__global__ __launch_bounds__(256) void k1_x4(const float* __restrict__ x,
                                             float* __restrict__ x4) {
  __shared__ float ls[3][1344];
  __shared__ float part[252];
  int b = blockIdx.x;                 // 256 blocks
  int n = b >> 2, q = b & 3;
  int tid = threadIdx.x;
  for (int idx = tid; idx < 1008; idx += 256) {   // 1008 f32x4 total
    int ci = idx / 336;
    int off = idx - ci * 336;
    ((f32x4*)ls)[idx] =
        ((const f32x4*)(x + (n * 3 + ci) * 5376 + q * 1344))[off];
  }
  __syncthreads();
  if (tid < 252) {
    int ci = tid / 84, rest = tid - ci * 84;
    int tq = rest / 21, v = rest - tq * 21;
    float s = 0.f;
#pragma unroll
    for (int i = 0; i < 16; ++i) s += ls[ci][(tq * 16 + i) * 21 + v];
    part[tid] = s;
  }
  __syncthreads();
  if (tid < 63) {
    int ci = tid / 21, v = tid - ci * 21;
    const float* p = part + ci * 84 + v;
    x4[((n * 3 + ci) * 4 + q) * 21 + v] = p[0] + p[21] + p[42] + p[63];
  }
}

// ---------------------------------------------------------------------------
// k2: U[n][r][w][k] = sum_v A[k][v][w] * S[k][v]
//     S[k][v] = sum_ci W[o][ci]*X4[n][ci][q][v] + 64*b[o], g=r*3+k, o=g>>2, q=g&3
// ---------------------------------------------------------------------------
__global__ __launch_bounds__(64) void k2_u(const float* __restrict__ x4,
                                           const float* __restrict__ A,
                                           const float* __restrict__ W,
                                           const float* __restrict__ bias,
                                           float* __restrict__ U) {
  int nb = blockIdx.x;                // n*256 + r
  int n = nb >> 8, r = nb & 255;
  __shared__ float S[3][kV];
  int i = threadIdx.x;
  if (i < 3 * kV) {
    int k = i / kV, v = i - k * kV;
    int g = r * 3 + k;
    int o = g >> 2, q = g & 3;
    const float* xp = x4 + (n * 12 + q) * kV + v;
    S[k][v] = W[o * 3 + 0] * xp[0] + W[o * 3 + 1] * xp[4 * kV] +
              W[o * 3 + 2] * xp[8 * kV] + 64.f * bias[o];
  }
  __syncthreads();
  if (i < 3 * kV) {
    int w = i / 3, k = i - w * 3;
    const float* a = A + k * kV * kV + w;
    float z = 0.f;
#pragma unroll
    for (int v = 0; v < kV; ++v) z += a[v * kV] * S[k][v];
    U[(nb * kV + w) * 3 + k] = z;
  }
}

// ---------------------------------------------------------------------------
// k3 (fused): one block per channel ch. Wave j handles (r,w) of 64-group j:
// lane=n computes u, 9 moments shuffle-reduced over n -> LDS; then thread
// (j,co) evaluates the quadratic form; 256-thread reduce -> stats[ch].
// ---------------------------------------------------------------------------
__global__ __launch_bounds__(256) void k3_stats(
    const float* __restrict__ U, const float* __restrict__ W_emb,
    const float* __restrict__ b_emb, const float* __restrict__ pos,
    const float* __restrict__ gamma, const float* __restrict__ beta,
    float* __restrict__ stats) {
  __shared__ double md[4][9];
  __shared__ double red[2][4];
  int ch = blockIdx.x;
  int tid = threadIdx.x;
  int j = tid >> 6, lane = tid & 63;
  int inner = ch * 256 + j * 64;
  int r = inner / kNCh;
  int w = (inner - r * kNCh) >> 6;
  // phase 1: per-(r,w) moments over n (lane = n)
  const float* up = U + ((lane * 256 + r) * kV + w) * 3;
  double u0 = up[0], u1 = up[1], u2 = up[2];
  double m[9] = {u0 * u0, u0 * u1, u0 * u2, u1 * u1, u1 * u2,
                 u2 * u2, u0,      u1,      u2};
#pragma unroll
  for (int off = 1; off < 64; off <<= 1) {
#pragma unroll
    for (int i = 0; i < 9; ++i) m[i] += __shfl_xor(m[i], off);
  }
  if (lane == 0) {
#pragma unroll
    for (int i = 0; i < 9; ++i) md[j][i] = m[i];
  }
  __syncthreads();
  // phase 2: thread (j, co=lane)
  double we0 = W_emb[lane * 3 + 0], we1 = W_emb[lane * 3 + 1],
         we2 = W_emb[lane * 3 + 2];
  double c = (double)b_emb[lane] + (double)pos[w * 64 + lane];
  const double* mm = md[j];
  double lin = we0 * mm[6] + we1 * mm[7] + we2 * mm[8];
  double S1 = lin + 64.0 * c;
  double S2 = we0 * we0 * mm[0] + 2.0 * we0 * we1 * mm[1] +
              2.0 * we0 * we2 * mm[2] + we1 * we1 * mm[3] +
              2.0 * we1 * we2 * mm[4] + we2 * we2 * mm[5] +
              2.0 * c * lin + 64.0 * c * c;
#pragma unroll
  for (int off = 1; off < 64; off <<= 1) {
    S1 += __shfl_xor(S1, off);
    S2 += __shfl_xor(S2, off);
  }
  if (lane == 0) { red[0][j] = S1; red[1][j] = S2; }
  __syncthreads();
  if (tid == 0) {
    double T1 = red[0][0] + red[0][1] + red[0][2] + red[0][3];
    double T2 = red[1][0] + red[1][1] + red[1][2] + red[1][3];
    double mean = T1 * (1.0 / 16384.0);
    double var = T2 * (1.0 / 16384.0) - mean * mean;
    double inv = rsqrt(var + 1e-5);
    stats[ch * 2 + 0] = (float)((double)gamma[ch] * inv);
    stats[ch * 2 + 1] = (float)((double)beta[ch] - mean * (double)gamma[ch] * inv);
  }
}

// ---------------------------------------------------------------------------
// k4: elementwise epilogue, 8 floats/thread, two f32x4 NT stores.
// out flat index == BN-input flat index. 10752 blocks x 256.
// ---------------------------------------------------------------------------
__global__ __launch_bounds__(256) void k4_out(
    const float* __restrict__ U, const float* __restrict__ W_emb,
    const float* __restrict__ b_emb, const float* __restrict__ pos,
    const float* __restrict__ stats, float* __restrict__ out) {
  int b = blockIdx.x;                 // 0..10751
  int n = b / 168;
  int bi = b - n * 168;
  int inner0 = bi * 2048 + threadIdx.x * 8;   // 8-aligned
  int t6 = inner0 >> 6;                        // r*21 + w
  int r = t6 / 21;
  int w = t6 - r * 21;
  int co = inner0 & 63;                        // 8-aligned
  int ch = inner0 >> 8;
  const float* up = U + ((n * 256 + r) * kV + w) * 3;
  float u0 = up[0], u1 = up[1], u2 = up[2];
  float sc = stats[ch * 2 + 0], sh = stats[ch * 2 + 1];
  float res[8];
#pragma unroll
  for (int d = 0; d < 8; ++d) {
    const float* we = W_emb + (co + d) * 3;
    res[d] = (we[0] * u0 + we[1] * u1 + we[2] * u2 + b_emb[co + d] +
              pos[w * 64 + co + d]) * sc + sh;
  }
  float* outp = out + (size_t)n * kInner + inner0;
  f32x4 o0 = {res[0], res[1], res[2], res[3]};
  f32x4 o1 = {res[4], res[5], res[6], res[7]};
  __builtin_nontemporal_store(o0, (f32x4*)outp);
  __builtin_nontemporal_store(o1, (f32x4*)outp + 1);
}

extern "C" void kernel_launch(void* const* d_in, const int* in_sizes, int n_in,
                              void* d_out, int out_size, void* d_ws, size_t ws_size,
                              hipStream_t stream) {
  const float* x      = (const float*)d_in[0];
  const float* A      = (const float*)d_in[1];
  const float* conv_w = (const float*)d_in[2];
  const float* conv_b = (const float*)d_in[3];
  const float* W_emb  = (const float*)d_in[4];
  const float* b_emb  = (const float*)d_in[5];
  const float* pos    = (const float*)d_in[6];
  const float* gamma  = (const float*)d_in[7];
  const float* beta   = (const float*)d_in[8];
  float* out = (float*)d_out;
  float* ws  = (float*)d_ws;

  float* x4    = ws + X4_OFF;
  float* U     = ws + U_OFF;
  float* stats = ws + ST_OFF;

  k1_x4<<<256, 256, 0, stream>>>(x, x4);
  k2_u<<<64 * 256, 64, 0, stream>>>(x4, A, conv_w, conv_b, U);
  k3_stats<<<1344, 256, 0, stream>>>(U, W_emb, b_emb, pos, gamma, beta, stats);
  k4_out<<<10752, 256, 0, stream>>>(U, W_emb, b_emb, pos, stats, out);
}

// Round 5
// 59.393 us; speedup vs baseline: 1.0768x; 1.0768x over previous
//
#include <hip/hip_runtime.h>

namespace {
constexpr int kV    = 21;
constexpr int kNCh  = 1344;         // V*C_OUT
constexpr int kInner = kNCh * 256;  // 344064 elements per n

typedef float f32x4 __attribute__((ext_vector_type(4)));

// workspace layout (float offsets; M is double, 8B-aligned)
constexpr int X4_OFF = 0;                 // [64][3][4][21] = 16128 floats
constexpr int M_OFF  = 16384;             // doubles: [5376][9] -> 96768 floats
constexpr int ST_OFF = M_OFF + 5376 * 9 * 2;  // [1344][2] floats
}

// ---------------------------------------------------------------------------
// kA: X4[n][ci][q][v] = sum_{t=q*64..q*64+63} x[n][ci][t][v]
// one block per (n,q): coalesced f32x4 loads -> LDS -> 2-stage reduce
// ---------------------------------------------------------------------------
__global__ __launch_bounds__(256) void kA_x4(const float* __restrict__ x,
                                             float* __restrict__ x4) {
  __shared__ float ls[3][1344];
  __shared__ float part[252];
  int b = blockIdx.x;                 // 256 blocks
  int n = b >> 2, q = b & 3;
  int tid = threadIdx.x;
  for (int idx = tid; idx < 1008; idx += 256) {   // 1008 f32x4 total
    int ci = idx / 336;
    int off = idx - ci * 336;
    ((f32x4*)ls)[idx] =
        ((const f32x4*)(x + (n * 3 + ci) * 5376 + q * 1344))[off];
  }
  __syncthreads();
  if (tid < 252) {
    int ci = tid / 84, rest = tid - ci * 84;
    int tq = rest / 21, v = rest - tq * 21;
    float s = 0.f;
#pragma unroll
    for (int i = 0; i < 16; ++i) s += ls[ci][(tq * 16 + i) * 21 + v];
    part[tid] = s;
  }
  __syncthreads();
  if (tid < 63) {
    int ci = tid / 21, v = tid - ci * 21;
    const float* p = part + ci * 84 + v;
    x4[((n * 3 + ci) * 4 + q) * 21 + v] = p[0] + p[21] + p[42] + p[63];
  }
}

// ---------------------------------------------------------------------------
// kB: one block per r (256 blocks x 256 threads).
//  S[n][k][v] -> u[n][w][k] (all in LDS) -> per-(r,w) 9 moments over n -> M
//  S[k][v] = sum_ci W[o][ci]*x4[n][ci][q][v] + 64*b[o], g=r*3+k, o=g>>2, q=g&3
//  u[k] = sum_v A[k][v][w] * S[k][v]
// ---------------------------------------------------------------------------
__global__ __launch_bounds__(256) void kB_mom(const float* __restrict__ x4,
                                              const float* __restrict__ A,
                                              const float* __restrict__ W,
                                              const float* __restrict__ bias,
                                              double* __restrict__ M) {
  __shared__ float Sld[64 * 65];        // S[n][k*21+v], pitch 65
  __shared__ float At[3 * 21 * 22];     // A_t[k][w][v], pitch 22
  __shared__ float Uld[64 * 65];        // u[n][w*3+k], pitch 65
  __shared__ double P[21 * 8 * 9];      // partial moments
  int r = blockIdx.x;
  int tid = threadIdx.x;

  // stage A transposed: At[k][w][v] = A[k][v][w]
  for (int t = tid; t < 1323; t += 256) {
    int k = t / 441, rem = t - k * 441;
    int v = rem / 21, w = rem - v * 21;
    At[k * 462 + w * 22 + v] = A[t];
  }
  // phase 1: S
  for (int idx = tid; idx < 4032; idx += 256) {
    int n = idx / 63, kv = idx - n * 63;
    int k = kv / 21, v = kv - k * 21;
    int g = r * 3 + k;
    int o = g >> 2, q = g & 3;
    const float* xp = x4 + n * 252 + q * 21 + v;
    Sld[n * 65 + kv] = W[o * 3 + 0] * xp[0] + W[o * 3 + 1] * xp[84] +
                       W[o * 3 + 2] * xp[168] + 64.f * bias[o];
  }
  __syncthreads();
  // phase 2: u
  for (int idx = tid; idx < 1344; idx += 256) {
    int n = idx & 63, w = idx >> 6;
#pragma unroll
    for (int k = 0; k < 3; ++k) {
      const float* a = At + k * 462 + w * 22;
      const float* s = Sld + n * 65 + k * 21;
      float acc = 0.f;
#pragma unroll
      for (int v = 0; v < 21; ++v) acc += a[v] * s[v];
      Uld[n * 65 + w * 3 + k] = acc;
    }
  }
  __syncthreads();
  // phase 3a: partial moments over 8 n's
  if (tid < 168) {
    int w = tid / 8, i = tid - w * 8;
    double acc[9] = {0, 0, 0, 0, 0, 0, 0, 0, 0};
    for (int dn = 0; dn < 8; ++dn) {
      int n = i * 8 + dn;
      double u0 = Uld[n * 65 + w * 3 + 0];
      double u1 = Uld[n * 65 + w * 3 + 1];
      double u2 = Uld[n * 65 + w * 3 + 2];
      acc[0] += u0 * u0; acc[1] += u0 * u1; acc[2] += u0 * u2;
      acc[3] += u1 * u1; acc[4] += u1 * u2; acc[5] += u2 * u2;
      acc[6] += u0;      acc[7] += u1;      acc[8] += u2;
    }
#pragma unroll
    for (int m = 0; m < 9; ++m) P[(w * 8 + i) * 9 + m] = acc[m];
  }
  __syncthreads();
  // phase 3b: final reduce -> M[t6][9]
  if (tid < 189) {
    int w = tid / 9, m = tid - w * 9;
    double s = 0.0;
#pragma unroll
    for (int i = 0; i < 8; ++i) s += P[(w * 8 + i) * 9 + m];
    M[(r * 21 + w) * 9 + m] = s;
  }
}

// ---------------------------------------------------------------------------
// kB2: per-channel BN stats from moments. 4 channels/block, lane = co.
// ---------------------------------------------------------------------------
__global__ __launch_bounds__(256) void kB2_stats(
    const double* __restrict__ M, const float* __restrict__ W_emb,
    const float* __restrict__ b_emb, const float* __restrict__ pos,
    const float* __restrict__ gamma, const float* __restrict__ beta,
    float* __restrict__ stats) {
  int ch = blockIdx.x * 4 + (threadIdx.x >> 6);   // < 1344
  int co = threadIdx.x & 63;
  double we0 = W_emb[co * 3 + 0], we1 = W_emb[co * 3 + 1], we2 = W_emb[co * 3 + 2];
  double be = b_emb[co];
  double S1 = 0.0, S2 = 0.0;
#pragma unroll
  for (int j = 0; j < 4; ++j) {
    int t6 = ch * 4 + j;
    int w = t6 % 21;
    const double* m = M + t6 * 9;
    double c = be + (double)pos[w * 64 + co];
    double lin = we0 * m[6] + we1 * m[7] + we2 * m[8];
    S1 += lin + 64.0 * c;
    S2 += we0 * we0 * m[0] + 2.0 * we0 * we1 * m[1] + 2.0 * we0 * we2 * m[2] +
          we1 * we1 * m[3] + 2.0 * we1 * we2 * m[4] + we2 * we2 * m[5] +
          2.0 * c * lin + 64.0 * c * c;
  }
#pragma unroll
  for (int off = 1; off < 64; off <<= 1) {
    S1 += __shfl_xor(S1, off);
    S2 += __shfl_xor(S2, off);
  }
  if (co == 0) {
    double mean = S1 * (1.0 / 16384.0);
    double var = S2 * (1.0 / 16384.0) - mean * mean;
    double inv = rsqrt(var + 1e-5);
    stats[ch * 2 + 0] = (float)((double)gamma[ch] * inv);
    stats[ch * 2 + 1] = (float)((double)beta[ch] - mean * (double)gamma[ch] * inv);
  }
}

// ---------------------------------------------------------------------------
// kC: epilogue. One block per (n, 2048-inner chunk). Recomputes the <=3
// S-rows and 32 u-triples in LDS from x4, then 8 outputs/thread, NT stores.
// ---------------------------------------------------------------------------
__global__ __launch_bounds__(256) void kC_out(
    const float* __restrict__ x4, const float* __restrict__ A,
    const float* __restrict__ W, const float* __restrict__ bias,
    const float* __restrict__ W_emb, const float* __restrict__ b_emb,
    const float* __restrict__ pos, const float* __restrict__ stats,
    float* __restrict__ out) {
  __shared__ float Sld[3 * 64];      // S[rr][k*21+v]
  __shared__ float uld[32 * 4];      // u[t6_local][k]
  int b = blockIdx.x;                // 10752
  int n = b / 168;
  int bi = b - n * 168;
  int tid = threadIdx.x;
  int base = bi * 32;                // first t6
  int r0 = base / 21;
  int nR = (base + 31) / 21 - r0 + 1;   // <= 3
  // phase 1: S rows for nR r's
  if (tid < nR * 63) {
    int rr = tid / 63, kv = tid - rr * 63;
    int k = kv / 21, v = kv - k * 21;
    int g = (r0 + rr) * 3 + k;
    int o = g >> 2, q = g & 3;
    const float* xp = x4 + n * 252 + q * 21 + v;
    Sld[rr * 64 + kv] = W[o * 3 + 0] * xp[0] + W[o * 3 + 1] * xp[84] +
                        W[o * 3 + 2] * xp[168] + 64.f * bias[o];
  }
  __syncthreads();
  // phase 2: u for 32 t6 groups
  if (tid < 96) {
    int t6l = tid / 3, k = tid - t6l * 3;
    int t6 = base + t6l;
    int r = t6 / 21;
    int w = t6 - r * 21;
    const float* a = A + k * 441 + w;          // stride 21 over v
    const float* s = Sld + (r - r0) * 64 + k * 21;
    float acc = 0.f;
#pragma unroll
    for (int v = 0; v < 21; ++v) acc += a[v * 21] * s[v];
    uld[t6l * 4 + k] = acc;
  }
  __syncthreads();
  // phase 3: 8 outputs/thread
  int t6l = tid >> 3;
  int t6 = base + t6l;
  int w = t6 % 21;
  int co = (tid & 7) * 8;
  int ch = bi * 8 + (tid >> 5);
  int inner0 = bi * 2048 + tid * 8;
  float u0 = uld[t6l * 4 + 0], u1 = uld[t6l * 4 + 1], u2 = uld[t6l * 4 + 2];
  float sc = stats[ch * 2 + 0], sh = stats[ch * 2 + 1];
  float res[8];
#pragma unroll
  for (int d = 0; d < 8; ++d) {
    const float* we = W_emb + (co + d) * 3;
    res[d] = (we[0] * u0 + we[1] * u1 + we[2] * u2 + b_emb[co + d] +
              pos[w * 64 + co + d]) * sc + sh;
  }
  float* outp = out + (size_t)n * kInner + inner0;
  f32x4 o0 = {res[0], res[1], res[2], res[3]};
  f32x4 o1 = {res[4], res[5], res[6], res[7]};
  __builtin_nontemporal_store(o0, (f32x4*)outp);
  __builtin_nontemporal_store(o1, (f32x4*)outp + 1);
}

extern "C" void kernel_launch(void* const* d_in, const int* in_sizes, int n_in,
                              void* d_out, int out_size, void* d_ws, size_t ws_size,
                              hipStream_t stream) {
  const float* x      = (const float*)d_in[0];
  const float* A      = (const float*)d_in[1];
  const float* conv_w = (const float*)d_in[2];
  const float* conv_b = (const float*)d_in[3];
  const float* W_emb  = (const float*)d_in[4];
  const float* b_emb  = (const float*)d_in[5];
  const float* pos    = (const float*)d_in[6];
  const float* gamma  = (const float*)d_in[7];
  const float* beta   = (const float*)d_in[8];
  float* out = (float*)d_out;
  float* ws  = (float*)d_ws;

  float*  x4    = ws + X4_OFF;
  double* M     = (double*)(ws + M_OFF);
  float*  stats = ws + ST_OFF;

  kA_x4<<<256, 256, 0, stream>>>(x, x4);
  kB_mom<<<256, 256, 0, stream>>>(x4, A, conv_w, conv_b, M);
  kB2_stats<<<336, 256, 0, stream>>>(M, W_emb, b_emb, pos, gamma, beta, stats);
  kC_out<<<10752, 256, 0, stream>>>(x4, A, conv_w, conv_b, W_emb, b_emb, pos,
                                    stats, out);
}